// Round 10
// baseline (1281.743 us; speedup 1.0000x reference)
//
#include <hip/hip_runtime.h>
#include <math.h>

// BiLSTM-CRF, fp32. V=50000 B=64 T=256 D=256 H=256 C=32
//
// R9 = R8 protocol (tag-embedded 64-bit exchange words, relaxed sc1, LDS-only
// barriers) with 4 SEQS PER GROUP: 32 groups x 4 member-WGs = 128 WGs x 512thr.
// The per-step exchange latency (~2.5k cy: BC->store->IC visible->poll->b2)
// amortizes over 2x compute. tanh via 1-2/(expf(2x)+1) (one v_exp_f32).
//
// ws layout (floats):
//   xg    : [2][64][256][1024]          33554432
//   hcat  : [64][256][512]               8388608
//   em    : [64][256][32]                 524288
//   hx    : [2par][32grp][4seq][256] ull  131072 floats (512 KB)
//
// d_out: float32[16448] = paths[64][256] (as float) then best_score[64]

typedef unsigned long long ull;

__device__ __forceinline__ void bar_lds()
{
    asm volatile("s_waitcnt lgkmcnt(0)\n\ts_barrier" ::: "memory");
}

__device__ __forceinline__ float sigm(float x) { return 1.f / (1.f + expf(-x)); }
__device__ __forceinline__ float tanh_f(float x) { return 1.f - 2.f / (expf(2.f * x) + 1.f); }

// ---------------------------------------------------------------- K1: embed + input GEMM
__global__ __launch_bounds__(256) void k1_xgemm(
    const int* __restrict__ sent, const int* __restrict__ lens,
    const float* __restrict__ emb,
    const float* __restrict__ wih_f, const float* __restrict__ wih_b,
    const float* __restrict__ bih_f, const float* __restrict__ bhh_f,
    const float* __restrict__ bih_b, const float* __restrict__ bhh_b,
    float* __restrict__ xg)
{
    const int bid = blockIdx.x;          // 2048 = 2 dir * 128 mt * 8 nt
    const int dir = bid >> 10;
    const int rem = bid & 1023;
    const int mt = rem >> 3, nt = rem & 7;
    const int r0 = mt * 128, j0 = nt * 128;
    const int b = r0 >> 8, t0 = r0 & 255;
    const float* __restrict__ wih = dir ? wih_b : wih_f;
    const float* __restrict__ bih = dir ? bih_b : bih_f;
    const float* __restrict__ bhh = dir ? bhh_b : bhh_f;

    __shared__ __align__(16) float At[32][132];
    __shared__ __align__(16) float Bt[32][132];
    __shared__ int tok_s[128];

    const int tid = threadIdx.x;
    if (tid < 128) {
        int t = t0 + tid;
        int tt = t;
        if (dir) { int L = lens[b]; if (t < L) tt = L - 1 - t; }
        tok_s[tid] = sent[b * 256 + tt];
    }
    __syncthreads();

    float acc[8][8];
    #pragma unroll
    for (int i = 0; i < 8; ++i)
        #pragma unroll
        for (int j = 0; j < 8; ++j) acc[i][j] = 0.f;

    const int lrow = tid >> 3;
    const int l8 = tid & 7;
    const int tx = tid & 15, ty = tid >> 4;

    for (int kc = 0; kc < 256; kc += 32) {
        #pragma unroll
        for (int it = 0; it < 4; ++it) {
            int row = lrow + it * 32;
            float4 va = *(const float4*)(emb + (size_t)tok_s[row] * 256 + kc + l8 * 4);
            At[l8*4+0][row] = va.x; At[l8*4+1][row] = va.y;
            At[l8*4+2][row] = va.z; At[l8*4+3][row] = va.w;
            float4 vb = *(const float4*)(wih + (size_t)(j0 + row) * 256 + kc + l8 * 4);
            Bt[l8*4+0][row] = vb.x; Bt[l8*4+1][row] = vb.y;
            Bt[l8*4+2][row] = vb.z; Bt[l8*4+3][row] = vb.w;
        }
        __syncthreads();
        #pragma unroll
        for (int k = 0; k < 32; ++k) {
            float4 a0 = *(const float4*)&At[k][ty*8];
            float4 a1 = *(const float4*)&At[k][ty*8+4];
            float4 b0 = *(const float4*)&Bt[k][tx*8];
            float4 b1 = *(const float4*)&Bt[k][tx*8+4];
            float av[8] = {a0.x,a0.y,a0.z,a0.w,a1.x,a1.y,a1.z,a1.w};
            float bv[8] = {b0.x,b0.y,b0.z,b0.w,b1.x,b1.y,b1.z,b1.w};
            #pragma unroll
            for (int i = 0; i < 8; ++i)
                #pragma unroll
                for (int j = 0; j < 8; ++j)
                    acc[i][j] += av[i] * bv[j];
        }
        __syncthreads();
    }

    float bias[8];
    {
        float4 p0 = *(const float4*)(bih + j0 + tx*8);
        float4 p1 = *(const float4*)(bih + j0 + tx*8 + 4);
        float4 q0 = *(const float4*)(bhh + j0 + tx*8);
        float4 q1 = *(const float4*)(bhh + j0 + tx*8 + 4);
        bias[0]=p0.x+q0.x; bias[1]=p0.y+q0.y; bias[2]=p0.z+q0.z; bias[3]=p0.w+q0.w;
        bias[4]=p1.x+q1.x; bias[5]=p1.y+q1.y; bias[6]=p1.z+q1.z; bias[7]=p1.w+q1.w;
    }
    #pragma unroll
    for (int i = 0; i < 8; ++i) {
        int r = r0 + ty*8 + i;
        int t = r & 255;
        float* orow = xg + ((size_t)(dir*64 + b) * 256 + t) * 1024 + j0 + tx*8;
        float4 o0, o1;
        o0.x = acc[i][0]+bias[0]; o0.y = acc[i][1]+bias[1];
        o0.z = acc[i][2]+bias[2]; o0.w = acc[i][3]+bias[3];
        o1.x = acc[i][4]+bias[4]; o1.y = acc[i][5]+bias[5];
        o1.z = acc[i][6]+bias[6]; o1.w = acc[i][7]+bias[7];
        *(float4*)orow = o0;
        *(float4*)(orow + 4) = o1;
    }
}

// ---------------------------------------------------------------- K2: weight-stationary LSTM
// 128 WGs x 512 thr: member m = blockIdx>>5 (64-unit slice), group g = blockIdx&31
// (dir = g>>4, seqs b0..b0+3 = (g&15)*4..). Thread (kg=tid>>6, q=tid&63):
// 4 rows {gate=q>>4, units (q&15)*4..+3} x k[kg*32,+32) = 128 weights in regs.
// Step: A(4 seqs, 512 FMA) -> b1 -> {BC(256thr): reduce+cell+tagged sc1 store
// +hcat || loader(256thr): poll 4 tags==t+1, fill hs} -> b2.
__global__ __launch_bounds__(512)
__attribute__((amdgpu_waves_per_eu(2, 2)))
void k2_lstm(
    const float* __restrict__ whh_f, const float* __restrict__ whh_b,
    const float* __restrict__ xg, float* __restrict__ hcat,
    ull* __restrict__ hx)
{
    const int m = blockIdx.x >> 5;       // member / slice 0..3
    const int g = blockIdx.x & 31;       // group
    const int dir = g >> 4;
    const int b0 = (g & 15) * 4;
    const float* __restrict__ w = dir ? whh_b : whh_f;

    const int tid = threadIdx.x;
    const int kg = tid >> 6;             // 0..7 (wave-uniform)
    const int q  = tid & 63;
    const int gate = q >> 4;             // 0..3
    const int u0 = (q & 15) * 4;         // unit quad base
    const int kbase = kg * 32;
    const int j0 = gate * 256 + m * 64 + u0;   // global row base (4 rows)

    // ---- 128 weights -> register file, pinned with asm value barriers
    float4 wv[4][8];
    #pragma unroll
    for (int j = 0; j < 4; ++j) {
        const float* wp = w + (size_t)(j0 + j) * 256 + kbase;
        #pragma unroll
        for (int i = 0; i < 8; ++i)
            wv[j][i] = *(const float4*)(wp + i * 4);
    }
    #pragma unroll
    for (int j = 0; j < 4; ++j)
        #pragma unroll
        for (int i = 0; i < 8; ++i)
            asm volatile("" : "+v"(wv[j][i].x), "+v"(wv[j][i].y),
                              "+v"(wv[j][i].z), "+v"(wv[j][i].w));

    __shared__ __align__(16) float hs[4][256];        // h_{t-1}, 4 seqs
    __shared__ __align__(16) float red[8][4][256];    // 32 KB partials

    // BC mapping (tid<256): s_c = seq 0..3, ul = unit in slice
    const int s_c = tid >> 6, ul = tid & 63;
    const float* xgp = xg + (size_t)(dir * 64 + b0 + s_c) * 262144 + m * 64 + ul;
    ull* hx_w = hx + ((size_t)g * 4 + s_c) * 256 + m * 64 + ul;     // + par*32768
    float* hc_w = hcat + (size_t)(b0 + s_c) * 131072 + dir * 256 + m * 64 + ul;

    // loader mapping (tid in [256,512)): 4 units each
    const int tid2 = tid - 256;
    const int s_r = tid2 >> 6, pr = tid2 & 63;        // seq, unit-quad
    const ull* hx_r = hx + ((size_t)g * 4 + s_r) * 256 + 4 * pr;    // + par*32768

    ((float*)hs)[tid & 511] = 0.f;       // zero 512 of 1024
    ((float*)hs)[512 + (tid & 511)] = 0.f;
    float c_reg = 0.f;
    bar_lds();

    for (int t = 0; t < 256; ++t) {
        const int par = t & 1;

        // xg prefetch for BC (issued pre-A, latency hidden under A)
        float xp0 = 0.f, xp1 = 0.f, xp2 = 0.f, xp3 = 0.f;
        if (tid < 256) {
            const float* xq = xgp + (size_t)t * 1024;
            xp0 = xq[0]; xp1 = xq[256]; xp2 = xq[512]; xp3 = xq[768];
        }

        // ---- phase A: 4 rows x 4 seqs x 32 k from register weights
        float a[4][4];   // [row][seq]
        #pragma unroll
        for (int r = 0; r < 4; ++r)
            #pragma unroll
            for (int s = 0; s < 4; ++s) a[r][s] = 0.f;
        #pragma unroll
        for (int i = 0; i < 8; ++i) {
            float4 h0 = *(const float4*)&hs[0][kbase + i * 4];   // broadcast
            float4 h1 = *(const float4*)&hs[1][kbase + i * 4];
            float4 h2 = *(const float4*)&hs[2][kbase + i * 4];
            float4 h3 = *(const float4*)&hs[3][kbase + i * 4];
            #pragma unroll
            for (int r = 0; r < 4; ++r) {
                float4 wr = wv[r][i];
                a[r][0] += wr.x*h0.x + wr.y*h0.y + wr.z*h0.z + wr.w*h0.w;
                a[r][1] += wr.x*h1.x + wr.y*h1.y + wr.z*h1.z + wr.w*h1.w;
                a[r][2] += wr.x*h2.x + wr.y*h2.y + wr.z*h2.z + wr.w*h2.w;
                a[r][3] += wr.x*h3.x + wr.y*h3.y + wr.z*h3.z + wr.w*h3.w;
            }
        }
        #pragma unroll
        for (int s = 0; s < 4; ++s) {
            float4 rv; rv.x = a[0][s]; rv.y = a[1][s]; rv.z = a[2][s]; rv.w = a[3][s];
            *(float4*)&red[kg][s][q * 4] = rv;    // rows gate*64 + u0..u0+3
        }
        bar_lds();                                         // b1

        // ---- phase BC (waves 0-3)  ||  loader (waves 4-7)
        if (tid < 256) {
            float gi = xp0, gf = xp1, gg = xp2, go = xp3;
            #pragma unroll
            for (int kk = 0; kk < 8; ++kk) {
                gi += red[kk][s_c][ul];
                gf += red[kk][s_c][64 + ul];
                gg += red[kk][s_c][128 + ul];
                go += red[kk][s_c][192 + ul];
            }
            float si = sigm(gi);
            float sf = sigm(gf);
            float so = sigm(go);
            c_reg = sf * c_reg + si * tanh_f(gg);
            float hn = so * tanh_f(c_reg);
            ull pk = ((ull)(unsigned)(t + 1) << 32) | (ull)__float_as_uint(hn);
            __hip_atomic_store(hx_w + (size_t)par * 32768, pk,
                               __ATOMIC_RELAXED, __HIP_MEMORY_SCOPE_AGENT);
            hc_w[(size_t)t * 512] = hn;          // fire & forget (no drain: bar_lds)
        } else {
            const unsigned tg = (unsigned)(t + 1);
            const ull* p = hx_r + (size_t)par * 32768;
            ull v0, v1, v2, v3;
            do {
                v0 = __hip_atomic_load(p,     __ATOMIC_RELAXED, __HIP_MEMORY_SCOPE_AGENT);
                v1 = __hip_atomic_load(p + 1, __ATOMIC_RELAXED, __HIP_MEMORY_SCOPE_AGENT);
                v2 = __hip_atomic_load(p + 2, __ATOMIC_RELAXED, __HIP_MEMORY_SCOPE_AGENT);
                v3 = __hip_atomic_load(p + 3, __ATOMIC_RELAXED, __HIP_MEMORY_SCOPE_AGENT);
            } while ((unsigned)(v0 >> 32) != tg || (unsigned)(v1 >> 32) != tg ||
                     (unsigned)(v2 >> 32) != tg || (unsigned)(v3 >> 32) != tg);
            hs[s_r][4 * pr]     = __uint_as_float((unsigned)v0);
            hs[s_r][4 * pr + 1] = __uint_as_float((unsigned)v1);
            hs[s_r][4 * pr + 2] = __uint_as_float((unsigned)v2);
            hs[s_r][4 * pr + 3] = __uint_as_float((unsigned)v3);
        }
        bar_lds();                                         // b2
    }
}

// ---------------------------------------------------------------- K3: emissions
__global__ __launch_bounds__(256) void k3_emis(
    const float* __restrict__ hcat, const float* __restrict__ wout,
    const float* __restrict__ bout, const int* __restrict__ lens,
    float* __restrict__ em)
{
    const int b = blockIdx.x >> 3;
    const int tt0 = (blockIdx.x & 7) * 32;
    __shared__ float wsw[512 * 32];
    const int tid = threadIdx.x;
    for (int i = tid; i < 16384; i += 256) {
        int c_ = i >> 9, k_ = i & 511;
        wsw[k_ * 32 + ((k_ + c_) & 31)] = wout[i];
    }
    __syncthreads();
    const int c = tid & 31, tq = tid >> 5;
    const int L = lens[b];
    float acc[4];
    const float* hfp[4];
    const float* hbp[4];
    int tv[4];
    #pragma unroll
    for (int i = 0; i < 4; ++i) {
        int t = tt0 + i * 8 + tq;
        tv[i] = t;
        int tr = (t < L) ? (L - 1 - t) : t;
        hfp[i] = hcat + ((size_t)b * 256 + t) * 512;
        hbp[i] = hcat + ((size_t)b * 256 + tr) * 512 + 256;
        acc[i] = bout[c];
    }
    for (int k = 0; k < 256; k += 4) {
        float w0 = wsw[(k+0)*32 + ((k+0+c)&31)];
        float w1 = wsw[(k+1)*32 + ((k+1+c)&31)];
        float w2_ = wsw[(k+2)*32 + ((k+2+c)&31)];
        float w3 = wsw[(k+3)*32 + ((k+3+c)&31)];
        #pragma unroll
        for (int i = 0; i < 4; ++i) {
            float4 h = *(const float4*)(hfp[i] + k);
            acc[i] += h.x*w0 + h.y*w1 + h.z*w2_ + h.w*w3;
        }
        float v0 = wsw[(256+k+0)*32 + ((256+k+0+c)&31)];
        float v1 = wsw[(256+k+1)*32 + ((256+k+1+c)&31)];
        float v2 = wsw[(256+k+2)*32 + ((256+k+2+c)&31)];
        float v3 = wsw[(256+k+3)*32 + ((256+k+3+c)&31)];
        #pragma unroll
        for (int i = 0; i < 4; ++i) {
            float4 h = *(const float4*)(hbp[i] + k);
            acc[i] += h.x*v0 + h.y*v1 + h.z*v2 + h.w*v3;
        }
    }
    #pragma unroll
    for (int i = 0; i < 4; ++i)
        em[((size_t)b * 256 + tv[i]) * 32 + c] = acc[i];
}

// ---------------------------------------------------------------- K4: Viterbi fwd + backtrace
__global__ __launch_bounds__(256) void k4_viterbi(
    const float* __restrict__ em, const int* __restrict__ lens,
    const float* __restrict__ strans, const float* __restrict__ etrans,
    const float* __restrict__ trans, float* __restrict__ out)
{
    const int b = blockIdx.x;
    __shared__ float em_s[8192];
    __shared__ float trans_t[32 * 33];
    __shared__ float score_s[32];
    __shared__ float fin[32];
    __shared__ unsigned char hist[256][32];
    __shared__ unsigned char path[256];
    __shared__ float bs_s;
    const int tid = threadIdx.x;
    for (int i = tid; i < 8192; i += 256) em_s[i] = em[(size_t)b * 8192 + i];
    for (int i = tid; i < 1024; i += 256) {
        int p = i >> 5, cc = i & 31;
        trans_t[cc * 33 + p] = trans[i];
    }
    __syncthreads();
    if (tid < 32) score_s[tid] = strans[tid] + em_s[tid];
    __syncthreads();
    const int c = tid >> 3, pg = tid & 7;
    const int L = lens[b];
    for (int t = 1; t < 256; ++t) {
        float v = -1e30f; int bi = 0;
        #pragma unroll
        for (int i = 0; i < 4; ++i) {
            int p = pg * 4 + i;
            float cand = score_s[p] + trans_t[c * 33 + p];
            if (cand > v) { v = cand; bi = p; }
        }
        #pragma unroll
        for (int off = 4; off >= 1; off >>= 1) {
            float ov = __shfl_down(v, off);
            int oi = __shfl_down(bi, off);
            if (ov > v) { v = ov; bi = oi; }
        }
        float ns = 0.f;
        if (pg == 0) {
            hist[t][c] = (unsigned char)bi;
            ns = (t < L) ? (v + em_s[t * 32 + c]) : score_s[c];
        }
        __syncthreads();
        if (pg == 0) score_s[c] = ns;
        __syncthreads();
    }
    if (tid < 32) fin[tid] = score_s[tid] + etrans[tid];
    __syncthreads();
    if (tid == 0) {
        float bv = -1e30f; int bl = 0;
        for (int cc = 0; cc < 32; ++cc)
            if (fin[cc] > bv) { bv = fin[cc]; bl = cc; }
        bs_s = bv;
        int tag = bl;
        path[255] = (unsigned char)tag;
        for (int t = 254; t >= 0; --t) {
            if (t < L - 1) tag = hist[t + 1][tag];
            path[t] = (unsigned char)tag;
        }
    }
    __syncthreads();
    out[(size_t)b * 256 + tid] = (float)path[tid];
    if (tid == 0) out[16384 + b] = bs_s;
}

// ---------------------------------------------------------------- launch
extern "C" void kernel_launch(void* const* d_in, const int* in_sizes, int n_in,
                              void* d_out, int out_size, void* d_ws, size_t ws_size,
                              hipStream_t stream)
{
    const int*   sent   = (const int*)  d_in[0];
    const int*   lens   = (const int*)  d_in[1];
    const float* emb    = (const float*)d_in[2];
    const float* wih_f  = (const float*)d_in[3];
    const float* whh_f  = (const float*)d_in[4];
    const float* bih_f  = (const float*)d_in[5];
    const float* bhh_f  = (const float*)d_in[6];
    const float* wih_b  = (const float*)d_in[7];
    const float* whh_b  = (const float*)d_in[8];
    const float* bih_b  = (const float*)d_in[9];
    const float* bhh_b  = (const float*)d_in[10];
    const float* wout   = (const float*)d_in[11];
    const float* bout   = (const float*)d_in[12];
    const float* strans = (const float*)d_in[13];
    const float* etrans = (const float*)d_in[14];
    const float* trans  = (const float*)d_in[15];
    float* out = (float*)d_out;

    float* ws   = (float*)d_ws;
    float* xg   = ws;                        // 33554432 floats
    float* hcat = xg + 33554432;             // 8388608
    float* em   = hcat + 8388608;            // 524288
    ull*   hx   = (ull*)(em + 524288);       // 65536 ull (512 KB), 8B-aligned

    hipLaunchKernelGGL(k1_xgemm, dim3(2048), dim3(256), 0, stream,
                       sent, lens, emb, wih_f, wih_b, bih_f, bhh_f, bih_b, bhh_b, xg);
    hipLaunchKernelGGL(k2_lstm, dim3(128), dim3(512), 0, stream,
                       whh_f, whh_b, xg, hcat, hx);
    hipLaunchKernelGGL(k3_emis, dim3(512), dim3(256), 0, stream,
                       hcat, wout, bout, lens, em);
    hipLaunchKernelGGL(k4_viterbi, dim3(64), dim3(256), 0, stream,
                       em, lens, strans, etrans, trans, out);
}